// Round 3
// baseline (335.774 us; speedup 1.0000x reference)
//
#include <hip/hip_runtime.h>

// ---------------------------------------------------------------------------
// TurboQuantAttention — round 3.
// 5 dispatches: prep_R / rotmax (rotate k,v,q + global absmax via atomicMax,
// no fp32 intermediates) / rotquant (recompute rotation deterministically,
// quantize -> kd natural + vdt2 tile-major-swizzled) / attn3 (2-wave blocks,
// 64 q-rows/wave (2 sets sharing every LDS read), dbuf DMA prefetch for K
// AND V, P in regs via S^T trick, fp16 orot) / unrot (fp16-in f16-MFMA).
// ---------------------------------------------------------------------------

typedef float    f32x4  __attribute__((ext_vector_type(4)));
typedef float    f32x16 __attribute__((ext_vector_type(16)));
typedef __bf16   bf16x8 __attribute__((ext_vector_type(8)));
typedef __bf16   bf16x4 __attribute__((ext_vector_type(4)));
typedef _Float16 f16x8  __attribute__((ext_vector_type(8)));
typedef short    s16x4  __attribute__((ext_vector_type(4)));
typedef unsigned int u32;
typedef unsigned int u32x4 __attribute__((ext_vector_type(4)));
typedef unsigned long long u64;

#define SLEN 2048
#define DH   128

static __device__ __forceinline__ f32x16 zero16() {
  f32x16 z;
#pragma unroll
  for (int i = 0; i < 16; ++i) z[i] = 0.f;
  return z;
}
static __device__ __forceinline__ f32x16 mfma_bf16_32x32x16(bf16x8 a, bf16x8 b, f32x16 c) {
  return __builtin_amdgcn_mfma_f32_32x32x16_bf16(a, b, c, 0, 0, 0);
}
static __device__ __forceinline__ f32x16 mfma_f16_32x32x16(f16x8 a, f16x8 b, f32x16 c) {
  return __builtin_amdgcn_mfma_f32_32x32x16_f16(a, b, c, 0, 0, 0);
}
static __device__ __forceinline__ f32x16 mfma_bf16_32x32x8(s16x4 a, s16x4 b, f32x16 c) {
  return __builtin_amdgcn_mfma_f32_32x32x8bf16_1k(a, b, c, 0, 0, 0);
}
static __device__ __forceinline__ void lds_dma16(const void* g, void* l) {
  __builtin_amdgcn_global_load_lds(
      (const __attribute__((address_space(1))) void*)(unsigned long long)g,
      (__attribute__((address_space(3))) void*)(unsigned int)(unsigned long long)l,
      16, 0, 0);
}

// quantize->dequantize, op-order identical to reference (fp32)
static __device__ __forceinline__ float qdq(float xr, float xmax, float qs) {
  float xs = xr / xmax * 3.5f;
  float xq = rintf(xs * 4.0f) * 0.25f;
  xq = fminf(3.5f, fmaxf(-3.5f, xq));
  float res = xs - xq;
  float sg = (res > 0.0f) ? 1.0f : ((res < 0.0f) ? -1.0f : 0.0f);
  float xc = xq + sg * qs * xmax;
  return xc / 3.5f * xmax;
}
static __device__ __forceinline__ unsigned short bfbits(float f) {
  __bf16 b = (__bf16)f;
  return __builtin_bit_cast(unsigned short, b);
}

// ---------------------------------------------------------------------------
__global__ __launch_bounds__(256) void prep_R(
    const float* __restrict__ R, _Float16* __restrict__ Bhi,
    _Float16* __restrict__ BhiT, _Float16* __restrict__ BloT)
{
  int i = blockIdx.x * 256 + threadIdx.x;   // 0..16383
  int kk = i >> 7, n = i & 127;
  float r = R[i];
  _Float16 h = (_Float16)r;
  _Float16 l = (_Float16)(r - (float)h);
  Bhi[i] = h;                          // [n][kk] view = R[n][kk] for X@R^T
  BhiT[n * 128 + kk] = h;              // [n][kk] = R[kk][n] for X@R
  BloT[n * 128 + kk] = l;
}

// ---------------------------------------------------------------------------
// rotmax: grid 1536. bid<512: k -> absmax(kvmax[0]); <1024: v -> kvmax[1];
// else: q -> qb bf16 scaled by 1/sqrt(128). 3-term f16 hi/lo for k/v
// (fp32-grade, preserves quantization bins), single-term for q.
// ---------------------------------------------------------------------------
__global__ __launch_bounds__(256) void rotmax_kernel(
    const float* __restrict__ q, const float* __restrict__ k,
    const float* __restrict__ v, const _Float16* __restrict__ Gh,
    const _Float16* __restrict__ Gl, __bf16* __restrict__ qb,
    int* __restrict__ kvmax_i)
{
  __shared__ __align__(16) char LB[65536];
  _Float16* BH = (_Float16*)LB;
  _Float16* BL = (_Float16*)(LB + 32768);

  const int bid = blockIdx.x;
  const int which = bid >> 9;               // 0=k 1=v 2=q
  const bool three = (which < 2);
  const float* X = (which == 0) ? k : (which == 1) ? v : q;
  const long r0 = (long)(bid & 511) * 128;

  const int tid = threadIdx.x, wave = tid >> 6, lane = tid & 63;
  const int r31 = lane & 31, hi = lane >> 5;

#pragma unroll
  for (int u = 0; u < 8; ++u) {
    int c = (wave * 8 + u) * 64 + lane;
    int n = c >> 4, p = c & 15, ch = p ^ (n & 7);
    lds_dma16(Gh + n * 128 + ch * 8, BH + (wave * 8 + u) * 512);
    if (three) lds_dma16(Gl + n * 128 + ch * 8, BL + (wave * 8 + u) * 512);
  }

  const long rowg = r0 + wave * 32 + r31;
  f16x8 ah[8], al[8];
#pragma unroll
  for (int t = 0; t < 8; ++t) {
    f32x4 x0 = *(const f32x4*)&X[rowg * 128 + t * 16 + hi * 8];
    f32x4 x1 = *(const f32x4*)&X[rowg * 128 + t * 16 + hi * 8 + 4];
#pragma unroll
    for (int j = 0; j < 4; ++j) {
      _Float16 h0 = (_Float16)x0[j]; ah[t][j] = h0;
      _Float16 h1 = (_Float16)x1[j]; ah[t][4 + j] = h1;
      al[t][j]     = (_Float16)(x0[j] - (float)h0);
      al[t][4 + j] = (_Float16)(x1[j] - (float)h1);
    }
  }
  __syncthreads();

  f32x16 acc[4];
#pragma unroll
  for (int ct = 0; ct < 4; ++ct) acc[ct] = zero16();
#pragma unroll
  for (int ct = 0; ct < 4; ++ct) {
#pragma unroll
    for (int t = 0; t < 8; ++t) {
      int idx = (ct * 32 + r31) * 128 + (((2 * t + hi) ^ (r31 & 7)) * 8);
      f16x8 bh = *(const f16x8*)&BH[idx];
      acc[ct] = mfma_f16_32x32x16(ah[t], bh, acc[ct]);
      if (three) {
        f16x8 bl = *(const f16x8*)&BL[idx];
        acc[ct] = mfma_f16_32x32x16(ah[t], bl, acc[ct]);
        acc[ct] = mfma_f16_32x32x16(al[t], bh, acc[ct]);
      }
    }
  }

  if (which == 2) {
    const float sc = 0.08838834764831843f;   // 1/sqrt(128)
#pragma unroll
    for (int ct = 0; ct < 4; ++ct)
#pragma unroll
      for (int r = 0; r < 16; ++r) {
        long grow = r0 + wave * 32 + (r & 3) + 8 * (r >> 2) + 4 * hi;
        qb[grow * 128 + ct * 32 + r31] = (__bf16)(acc[ct][r] * sc);
      }
  } else {
    float am = 0.f;
#pragma unroll
    for (int ct = 0; ct < 4; ++ct)
#pragma unroll
      for (int r = 0; r < 16; ++r) am = fmaxf(am, fabsf(acc[ct][r]));
#pragma unroll
    for (int m = 1; m <= 32; m <<= 1) am = fmaxf(am, __shfl_xor(am, m, 64));
    if (lane == 0) atomicMax(kvmax_i + which, __float_as_int(am));
  }
}

// ---------------------------------------------------------------------------
// rotquant: grid 1024. Recomputes the rotation (bit-identical to rotmax),
// applies qdq, writes: k -> kd bf16 natural [row][d];
// v -> vdt2 tile-major [head][kt][d][32 keys] with u64-chunk XOR swizzle
// (chunk c stored at c^(d&7)) so attn's linear DMA image is conflict-free.
// ---------------------------------------------------------------------------
__global__ __launch_bounds__(256) void rotquant_kernel(
    const float* __restrict__ k, const float* __restrict__ v,
    const _Float16* __restrict__ Gh, const _Float16* __restrict__ Gl,
    const int* __restrict__ kvmax_i, const float* __restrict__ qjl,
    __bf16* __restrict__ kd, u32* __restrict__ vdt2)
{
  __shared__ __align__(16) char LB[65536];
  _Float16* BH = (_Float16*)LB;
  _Float16* BL = (_Float16*)(LB + 32768);

  const int bid = blockIdx.x;
  const int which = bid >> 9;               // 0=k 1=v
  const float* X = which ? v : k;
  const long r0 = (long)(bid & 511) * 128;
  const float xmax = __int_as_float(kvmax_i[which]) + 1e-8f;
  const float qs = qjl[0];

  const int tid = threadIdx.x, wave = tid >> 6, lane = tid & 63;
  const int r31 = lane & 31, hi = lane >> 5;

#pragma unroll
  for (int u = 0; u < 8; ++u) {
    int c = (wave * 8 + u) * 64 + lane;
    int n = c >> 4, p = c & 15, ch = p ^ (n & 7);
    lds_dma16(Gh + n * 128 + ch * 8, BH + (wave * 8 + u) * 512);
    lds_dma16(Gl + n * 128 + ch * 8, BL + (wave * 8 + u) * 512);
  }

  const long rowg = r0 + wave * 32 + r31;
  f16x8 ah[8], al[8];
#pragma unroll
  for (int t = 0; t < 8; ++t) {
    f32x4 x0 = *(const f32x4*)&X[rowg * 128 + t * 16 + hi * 8];
    f32x4 x1 = *(const f32x4*)&X[rowg * 128 + t * 16 + hi * 8 + 4];
#pragma unroll
    for (int j = 0; j < 4; ++j) {
      _Float16 h0 = (_Float16)x0[j]; ah[t][j] = h0;
      _Float16 h1 = (_Float16)x1[j]; ah[t][4 + j] = h1;
      al[t][j]     = (_Float16)(x0[j] - (float)h0);
      al[t][4 + j] = (_Float16)(x1[j] - (float)h1);
    }
  }
  __syncthreads();

  f32x16 acc[4];
#pragma unroll
  for (int ct = 0; ct < 4; ++ct) acc[ct] = zero16();
#pragma unroll
  for (int ct = 0; ct < 4; ++ct) {
#pragma unroll
    for (int t = 0; t < 8; ++t) {
      int idx = (ct * 32 + r31) * 128 + (((2 * t + hi) ^ (r31 & 7)) * 8);
      f16x8 bh = *(const f16x8*)&BH[idx];
      f16x8 bl = *(const f16x8*)&BL[idx];
      acc[ct] = mfma_f16_32x32x16(ah[t], bh, acc[ct]);
      acc[ct] = mfma_f16_32x32x16(ah[t], bl, acc[ct]);
      acc[ct] = mfma_f16_32x32x16(al[t], bh, acc[ct]);
    }
  }

  if (which == 0) {
#pragma unroll
    for (int ct = 0; ct < 4; ++ct)
#pragma unroll
      for (int r = 0; r < 16; ++r) {
        long grow = r0 + wave * 32 + (r & 3) + 8 * (r >> 2) + 4 * hi;
        kd[grow * 128 + ct * 32 + r31] = (__bf16)qdq(acc[ct][r], xmax, qs);
      }
  } else {
    __syncthreads();                         // done reading BH/BL
    u32 (*T32)[68] = (u32(*)[68])LB;         // 128 x 68 u32 = 34816 B
    const int head = (int)(r0 >> 11);
    const int kt0 = ((int)r0 & 2047) >> 5;
#pragma unroll
    for (int ct = 0; ct < 4; ++ct) {
      int d = ct * 32 + r31;
#pragma unroll
      for (int r = 0; r < 16; r += 2) {
        int s_lo = (r & 3) + 8 * (r >> 2) + 4 * hi + 32 * wave;
        u32 lo = bfbits(qdq(acc[ct][r],     xmax, qs));
        u32 hb = bfbits(qdq(acc[ct][r + 1], xmax, qs));
        int c  = (s_lo & 31) >> 2;
        int pr = (s_lo >> 1) & 1;
        int ts = s_lo >> 5;
        T32[d][ts * 16 + ((c ^ (d & 7)) << 1) + pr] = lo | (hb << 16);
      }
    }
    __syncthreads();
    int d = tid >> 1, h = tid & 1;
    u32* gdst = vdt2 + (long)(head * 64 + kt0) * 2048 + d * 16;
#pragma unroll
    for (int i = 0; i < 2; ++i) {
      int ts = h * 2 + i;
      const u32* src = &T32[d][ts * 16];
      u32x4* dst = (u32x4*)(gdst + ts * 2048);
      dst[0] = *(const u32x4*)(src);
      dst[1] = *(const u32x4*)(src + 4);
      dst[2] = *(const u32x4*)(src + 8);
      dst[3] = *(const u32x4*)(src + 12);
    }
  }
}

// ---------------------------------------------------------------------------
// attn3: 512 blocks x 128 thr (2 waves). Wave = 64 q-rows (2 sets of 32);
// every K/V LDS read feeds 2 MFMAs. Double-buffered DMA prefetch: tile kt+1
// issued right after the barrier that publishes kt -> a full compute phase
// of flight before the next barrier drains it.
// ---------------------------------------------------------------------------
__global__ __launch_bounds__(128, 1) void attn3(
    const __bf16* __restrict__ qb, const __bf16* __restrict__ kd,
    const u64* __restrict__ vdt2, const int* __restrict__ kvmax_i,
    const float* __restrict__ qjl, _Float16* __restrict__ orot)
{
  __shared__ __bf16 Ks[2][4096];    // 8KB per buf, XOR-swizzled 16B chunks
  __shared__ u64   Vq[2][1024];     // 8KB per buf, linear DMA image (pre-swizzled)
  __shared__ float Ls[2][64];

  const int tid = threadIdx.x, w = tid >> 6, lane = tid & 63;
  const int r31 = lane & 31, hi = lane >> 5;
  const int head = blockIdx.x & 31, qt = blockIdx.x >> 5;
  const long hrow = (long)head * SLEN;
  const int qrow0 = qt * 128 + w * 64;

  const float xmax = __int_as_float(kvmax_i[0]) + 1e-8f;
  const float Bk = 11.313708499f * ((3.5f + qjl[0] * xmax) * xmax / 3.5f) * 1.02f * 0.5f;

  // Q fragments (B-layout of 32x32x16) + row norm -> static softmax bound
  bf16x8 qf[2][8];
  float Mq[2], ls[2] = {0.f, 0.f};
#pragma unroll
  for (int qs = 0; qs < 2; ++qs) {
    float n2 = 0.f;
#pragma unroll
    for (int t = 0; t < 8; ++t) {
      qf[qs][t] = *(const bf16x8*)&qb[(hrow + qrow0 + qs * 32 + r31) * DH + t * 16 + hi * 8];
#pragma unroll
      for (int j = 0; j < 8; ++j) { float f = (float)qf[qs][t][j]; n2 += f * f; }
    }
    n2 += __shfl_xor(n2, 32, 64);
    Mq[qs] = sqrtf(n2) * Bk;
  }

  int koff[8];
#pragma unroll
  for (int t = 0; t < 8; ++t)
    koff[t] = r31 * 256 + (((2 * t + hi) ^ (r31 & 7)) << 4);   // bytes
  int vswz[4];
#pragma unroll
  for (int st = 0; st < 4; ++st) vswz[st] = (st * 2 + hi) ^ (r31 & 7);

  long gk[4]; int lk[4];
#pragma unroll
  for (int u = 0; u < 4; ++u) {
    int c = (w * 4 + u) * 64 + lane;
    int row = c >> 4, ch = (c & 15) ^ (row & 7);
    gk[u] = (hrow + row) * DH + ch * 8;
    lk[u] = (w * 4 + u) * 1024;       // bytes
  }
  const char* vbase = (const char*)vdt2 + (long)head * 64 * 8192;

  f32x16 acc[2][4];
#pragma unroll
  for (int qs = 0; qs < 2; ++qs)
#pragma unroll
    for (int dt = 0; dt < 4; ++dt) acc[qs][dt] = zero16();

  // prologue: stage tile 0
#pragma unroll
  for (int u = 0; u < 4; ++u) {
    lds_dma16(kd + gk[u], (char*)Ks[0] + lk[u]);
    lds_dma16(vbase + lk[u] + lane * 16, (char*)Vq[0] + lk[u]);
  }

  for (int kt = 0; kt < SLEN / 32; ++kt) {
    const int cur = kt & 1;
    __syncthreads();                 // publish tile kt (prefetch had full compute to fly)
    if (kt < SLEN / 32 - 1) {
      const int nb = cur ^ 1;
#pragma unroll
      for (int u = 0; u < 4; ++u) {
        lds_dma16(kd + gk[u] + (long)(kt + 1) * 32 * DH, (char*)Ks[nb] + lk[u]);
        lds_dma16(vbase + (long)(kt + 1) * 8192 + lk[u] + lane * 16, (char*)Vq[nb] + lk[u]);
      }
    }

    // S^T = K Q^T for both q-sets (K A-frags shared)
    const char* ksb = (const char*)Ks[cur];
    f32x16 s0 = zero16(), s1 = zero16();
#pragma unroll
    for (int t = 0; t < 8; ++t) {
      bf16x8 ka = *(const bf16x8*)(ksb + koff[t]);
      s0 = mfma_bf16_32x32x16(ka, qf[0][t], s0);
      s1 = mfma_bf16_32x32x16(ka, qf[1][t], s1);
    }

    float p0[16], p1[16];
#pragma unroll
    for (int r = 0; r < 16; ++r) {
      p0[r] = __expf(s0[r] - Mq[0]); ls[0] += p0[r];
      p1[r] = __expf(s1[r] - Mq[1]); ls[1] += p1[r];
    }

    // PV (V b64 reads shared across q-sets)
    const u64* vq = Vq[cur];
#pragma unroll
    for (int st = 0; st < 4; ++st) {
      bf16x4 b0, b1;
#pragma unroll
      for (int j = 0; j < 4; ++j) { b0[j] = (__bf16)p0[st * 4 + j]; b1[j] = (__bf16)p1[st * 4 + j]; }
      s16x4 pa0 = __builtin_bit_cast(s16x4, b0);
      s16x4 pa1 = __builtin_bit_cast(s16x4, b1);
#pragma unroll
      for (int dt = 0; dt < 4; ++dt) {
        s16x4 vb = __builtin_bit_cast(s16x4, vq[(dt * 32 + r31) * 8 + vswz[st]]);
        acc[0][dt] = mfma_bf16_32x32x8(pa0, vb, acc[0][dt]);
        acc[1][dt] = mfma_bf16_32x32x8(pa1, vb, acc[1][dt]);
      }
    }
  }

#pragma unroll
  for (int qs = 0; qs < 2; ++qs) {
    float t = ls[qs] + __shfl_xor(ls[qs], 32, 64);
    if (hi == 0) Ls[w][qs * 32 + r31] = 1.0f / t;
  }
  __syncthreads();
#pragma unroll
  for (int qs = 0; qs < 2; ++qs)
#pragma unroll
    for (int dt = 0; dt < 4; ++dt)
#pragma unroll
      for (int r = 0; r < 16; ++r) {
        int qr = (r & 3) + 8 * (r >> 2) + 4 * hi;
        float o = acc[qs][dt][r] * Ls[w][qs * 32 + qr];
        orot[(hrow + qrow0 + qs * 32 + qr) * DH + dt * 32 + r31] = (_Float16)o;
      }
}

// ---------------------------------------------------------------------------
// unrot: OUT = O16 @ R^T, fp16 A-operand direct (no conversion), fp32 out.
// ---------------------------------------------------------------------------
__global__ __launch_bounds__(256) void unrot_kernel(
    const _Float16* __restrict__ O16, const _Float16* __restrict__ Gh,
    float* __restrict__ OUT)
{
  __shared__ __align__(16) _Float16 BH[16384];
  const int tid = threadIdx.x, wave = tid >> 6, lane = tid & 63;
  const int r31 = lane & 31, hi = lane >> 5;
  const long r0 = (long)blockIdx.x * 128;

#pragma unroll
  for (int u = 0; u < 8; ++u) {
    int c = (wave * 8 + u) * 64 + lane;
    int n = c >> 4, p = c & 15, ch = p ^ (n & 7);
    lds_dma16(Gh + n * 128 + ch * 8, BH + (wave * 8 + u) * 512);
  }

  const long rowg = r0 + wave * 32 + r31;
  f16x8 ah[8];
#pragma unroll
  for (int t = 0; t < 8; ++t)
    ah[t] = *(const f16x8*)&O16[rowg * 128 + t * 16 + hi * 8];
  __syncthreads();

  f32x16 acc[4];
#pragma unroll
  for (int ct = 0; ct < 4; ++ct) acc[ct] = zero16();
#pragma unroll
  for (int ct = 0; ct < 4; ++ct) {
#pragma unroll
    for (int t = 0; t < 8; ++t) {
      int idx = (ct * 32 + r31) * 128 + (((2 * t + hi) ^ (r31 & 7)) * 8);
      f16x8 bh = *(const f16x8*)&BH[idx];
      acc[ct] = mfma_f16_32x32x16(ah[t], bh, acc[ct]);
    }
  }
#pragma unroll
  for (int ct = 0; ct < 4; ++ct)
#pragma unroll
    for (int r = 0; r < 16; ++r) {
      long grow = r0 + wave * 32 + (r & 3) + 8 * (r >> 2) + 4 * hi;
      OUT[grow * 128 + ct * 32 + r31] = acc[ct][r];
    }
}

// ---------------------------------------------------------------------------
extern "C" void kernel_launch(void* const* d_in, const int* in_sizes, int n_in,
                              void* d_out, int out_size, void* d_ws, size_t ws_size,
                              hipStream_t stream)
{
  const float* q   = (const float*)d_in[0];
  const float* k   = (const float*)d_in[1];
  const float* v   = (const float*)d_in[2];
  const float* R   = (const float*)d_in[3];
  const float* qjl = (const float*)d_in[4];

  char* ws = (char*)d_ws;
  int* kvmax_i = (int*)ws;                                  // 8 B (poison OK: negative)
  _Float16* Bhi  = (_Float16*)(ws + 1024);                  // 32 KB
  _Float16* BhiT = (_Float16*)(ws + 1024 + 32768);          // 32 KB
  _Float16* BloT = (_Float16*)(ws + 1024 + 65536);          // 32 KB
  char* base = ws + 1024 + 131072;
  __bf16*   qb   = (__bf16*)(base);                         // 16 MiB
  __bf16*   kd   = (__bf16*)(base + (16u << 20));           // 16 MiB
  u32*      vdt2 = (u32*)(base + (32u << 20));              // 16 MiB
  _Float16* orot = (_Float16*)(base + (48u << 20));         // 16 MiB

  dim3 b256(256);
  prep_R<<<64, b256, 0, stream>>>(R, Bhi, BhiT, BloT);
  rotmax_kernel<<<1536, b256, 0, stream>>>(q, k, v, BhiT, BloT, qb, kvmax_i);
  rotquant_kernel<<<1024, b256, 0, stream>>>(k, v, BhiT, BloT, kvmax_i, qjl, kd, vdt2);
  attn3<<<512, dim3(128), 0, stream>>>(qb, kd, (const u64*)vdt2, kvmax_i, qjl, orot);
  unrot_kernel<<<512, b256, 0, stream>>>(orot, Bhi, (float*)d_out);
}